// Round 6
// baseline (765.584 us; speedup 1.0000x reference)
//
#include <hip/hip_runtime.h>

#define HDIM 128
#define SEQ  14
#define G4   512
#define TLEN 8
#define EPB  2      // batch elements per block -> 256 blocks, all CUs
#define NTHR 512
#define HROW 136    // hbuf row pitch in halves (68 words; uniform 8/bank = b128 floor)
#define CTXW 20     // ctxT row pitch in floats (16B-aligned f32x4 loads)

typedef _Float16 half8 __attribute__((ext_vector_type(8)));
typedef float f32x4 __attribute__((ext_vector_type(4)));

__device__ __forceinline__ float frcp_(float x) { return __builtin_amdgcn_rcpf(x); }
__device__ __forceinline__ float fsig_(float x) { return frcp_(1.0f + __expf(-x)); }
__device__ __forceinline__ float ftanh_(float x) {
    return 1.0f - 2.0f * frcp_(__expf(2.0f * x) + 1.0f);
}

struct __align__(16) SMem {
    _Float16 hbuf[2][16][HROW];        // h, MFMA-A rows; rows 0,1 live, 2..15 quarantine
    _Float16 ench[SEQ][EPB][HDIM];     // encoder outputs (f16)
    _Float16 encWe[SEQ][EPB][HDIM];    // enc_out @ We (f16)
    _Float16 hWdh[EPB][HDIM];          // h @ Wd (f16)
    float ctxT[HDIM + 1][CTXW];        // ctx dim-major; row 128 = x; cols>=EPB stay 0
    float inpT[SEQ][16];               // encoder inputs, rows >= EPB zero
    float attnw[EPB][SEQ];
    float asum[EPB][SEQ];
    float score[EPB][SEQ];
    float wv[HDIM];
    float wf[HDIM];
};

__global__ __launch_bounds__(NTHR, 2) void seq2seq_kernel(
    const float* __restrict__ inputs,
    const float* __restrict__ Wih_e, const float* __restrict__ Whh_e, const float* __restrict__ b_e,
    const float* __restrict__ Wih_d, const float* __restrict__ Whh_d, const float* __restrict__ b_d,
    const float* __restrict__ We, const float* __restrict__ Wd,
    const float* __restrict__ Wv, const float* __restrict__ Wf, const float* __restrict__ bfp,
    float* __restrict__ out, int B)
{
    const int tid  = threadIdx.x;
    const int b0   = blockIdx.x * EPB;
    const int w    = tid >> 6;       // wave: gate-cols [16w,16w+16) of each gate
    const int lane = tid & 63;
    const int q    = lane >> 4;
    const int l    = lane & 15;
    __shared__ SMem S;

    // ---- init ----
    if (tid < 2 * HDIM) {
        int e = tid >> 7, j = tid & 127;
        S.hbuf[0][e][j] = (_Float16)0.0f;
        S.hbuf[1][e][j] = (_Float16)0.0f;
    }
    for (int i = tid; i < (HDIM + 1) * CTXW; i += NTHR) ((float*)S.ctxT)[i] = 0.0f;
    if (tid < SEQ * 16) {
        int t = tid >> 4, m = tid & 15;
        S.inpT[t][m] = (m < EPB) ? inputs[(b0 + m) * SEQ + t] : 0.0f;
    }
    if (tid < EPB * SEQ) { int e = tid / SEQ, t = tid % SEQ; S.asum[e][t] = 0.0f; }
    if (tid < HDIM) { S.wv[tid] = Wv[tid]; S.wf[tid] = Wf[tid]; }

    // ---- encoder recurrent weights (B-frag) ----
    half8 whh[4][4];
    float wihg[4], bg[4];
    #pragma unroll
    for (int g = 0; g < 4; ++g) {
        int n = g * HDIM + 16 * w + l;
        wihg[g] = Wih_e[n];
        bg[g]   = b_e[n];
        #pragma unroll
        for (int kt = 0; kt < 4; ++kt) {
            half8 f;
            #pragma unroll
            for (int jj = 0; jj < 8; ++jj)
                f[jj] = (_Float16)Whh_e[(32 * kt + 8 * q + jj) * G4 + n];
            whh[g][kt] = f;
        }
    }
    float c = 0.0f;   // cell state: lane (q<2,l) of wave w holds c[elem=q][col=16w+l]
    __syncthreads();

    int cur = 0;
    half8 af[4];
    f32x4 xv;
    // preload for encoder t=0
    {
        const _Float16* hr = &S.hbuf[cur][l][0];
        #pragma unroll
        for (int kt = 0; kt < 4; ++kt) af[kt] = *(const half8*)&hr[32 * kt + 8 * q];
        xv = *(const f32x4*)&S.inpT[0][4 * q];
    }

    // ---- encoder: 14 steps, one barrier each ----
    for (int t = 0; t < SEQ; ++t) {
        f32x4 acc[4];
        #pragma unroll
        for (int g = 0; g < 4; ++g)
            #pragma unroll
            for (int r = 0; r < 4; ++r)
                acc[g][r] = fmaf(xv[r], wihg[g], bg[g]);
        #pragma unroll
        for (int g = 0; g < 4; ++g)
            #pragma unroll
            for (int kt = 0; kt < 4; ++kt)
                acc[g] = __builtin_amdgcn_mfma_f32_16x16x32_f16(af[kt], whh[g][kt], acc[g], 0, 0, 0);
        // move elem1 gates (row1, in q=0 lanes) to q=1 lanes; activate both in one stream
        float s0 = __shfl_xor(acc[0][1], 16, 64);
        float s1 = __shfl_xor(acc[1][1], 16, 64);
        float s2 = __shfl_xor(acc[2][1], 16, 64);
        float s3 = __shfl_xor(acc[3][1], 16, 64);
        float v0 = (q == 0) ? acc[0][0] : s0;
        float v1 = (q == 0) ? acc[1][0] : s1;
        float v2 = (q == 0) ? acc[2][0] : s2;
        float v3 = (q == 0) ? acc[3][0] : s3;
        float ig = fsig_(v0), fg = fsig_(v1), gg = ftanh_(v2), og = fsig_(v3);
        c = fmaf(fg, c, ig * gg);
        float hn = og * ftanh_(c);
        int nxt = cur ^ 1;
        if (q < 2) {
            _Float16 hh = (_Float16)hn;
            S.hbuf[nxt][q][16 * w + l] = hh;
            S.ench[t][q][16 * w + l]   = hh;
        }
        __syncthreads();
        cur = nxt;
        if (t < SEQ - 1) {
            const _Float16* hr = &S.hbuf[cur][l][0];
            #pragma unroll
            for (int kt = 0; kt < 4; ++kt) af[kt] = *(const half8*)&hr[32 * kt + 8 * q];
            xv = *(const f32x4*)&S.inpT[t + 1][4 * q];
        }
    }

    // ---- encWe = enc_out @ We (one-time) ----
    {
        half8 wef[4];
        int n = 16 * w + l;
        #pragma unroll
        for (int kt = 0; kt < 4; ++kt) {
            half8 f;
            #pragma unroll
            for (int jj = 0; jj < 8; ++jj)
                f[jj] = (_Float16)We[(32 * kt + 8 * q + jj) * HDIM + n];
            wef[kt] = f;
        }
        for (int t = 0; t < SEQ; ++t) {
            const _Float16* er = &S.ench[t][l][0];   // rows l>=2: in-struct garbage, rows 0,1 clean
            f32x4 dv = {0.f, 0.f, 0.f, 0.f};
            #pragma unroll
            for (int kt = 0; kt < 4; ++kt) {
                half8 a = *(const half8*)&er[32 * kt + 8 * q];
                dv = __builtin_amdgcn_mfma_f32_16x16x32_f16(a, wef[kt], dv, 0, 0, 0);
            }
            if (q == 0) {
                S.encWe[t][0][n] = (_Float16)dv[0];
                S.encWe[t][1][n] = (_Float16)dv[1];
            }
        }
    }

    // ---- decoder weights ----
    half8 wdf[4];
    #pragma unroll
    for (int g = 0; g < 4; ++g) {
        int n = g * HDIM + 16 * w + l;
        wihg[g] = Wih_d[n];
        bg[g]   = b_d[n];
        #pragma unroll
        for (int kt = 0; kt < 4; ++kt) {
            half8 f;
            #pragma unroll
            for (int jj = 0; jj < 8; ++jj)
                f[jj] = (_Float16)Whh_d[(32 * kt + 8 * q + jj) * G4 + n];
            whh[g][kt] = f;
        }
    }
    {
        int n = 16 * w + l;
        #pragma unroll
        for (int kt = 0; kt < 4; ++kt) {
            half8 f;
            #pragma unroll
            for (int jj = 0; jj < 8; ++jj)
                f[jj] = (_Float16)Wd[(32 * kt + 8 * q + jj) * HDIM + n];
            wdf[kt] = f;
        }
    }
    float bf0 = bfp[0];
    if (tid < EPB) S.ctxT[HDIM][tid] = inputs[(b0 + tid) * SEQ + (SEQ - 1)];
    __syncthreads();   // encWe + x0 visible

    // ---- decoder: 8 steps ----
    for (int d = 0; d < TLEN; ++d) {
        // hWd = h @ Wd
        {
            const _Float16* hr = &S.hbuf[cur][l][0];
            f32x4 dv = {0.f, 0.f, 0.f, 0.f};
            #pragma unroll
            for (int kt = 0; kt < 4; ++kt) {
                half8 a = *(const half8*)&hr[32 * kt + 8 * q];
                dv = __builtin_amdgcn_mfma_f32_16x16x32_f16(a, wdf[kt], dv, 0, 0, 0);
            }
            if (q == 0) {
                int n = 16 * w + l;
                S.hWdh[0][n] = (_Float16)dv[0];
                S.hWdh[1][n] = (_Float16)dv[1];
            }
        }
        __syncthreads();
        // scores
        if (tid < 2 * SEQ * 16) {
            int p = tid >> 4, sub = tid & 15;
            int m = p & 1, t = p >> 1;
            const _Float16* ew = &S.encWe[t][m][0];
            const _Float16* hw = &S.hWdh[m][0];
            float s = 0.0f;
            #pragma unroll
            for (int i = 0; i < 8; ++i) {
                int j = sub * 8 + i;
                s = fmaf(ftanh_((float)ew[j] + (float)hw[j]), S.wv[j], s);
            }
            s += __shfl_down(s, 8, 16);
            s += __shfl_down(s, 4, 16);
            s += __shfl_down(s, 2, 16);
            s += __shfl_down(s, 1, 16);
            if (sub == 0) S.score[m][t] = s;
        }
        __syncthreads();
        // softmax over 14 per element
        if (tid < EPB) {
            int m = tid;
            float sc[SEQ]; float mx = -1e30f;
            #pragma unroll
            for (int t = 0; t < SEQ; ++t) { sc[t] = S.score[m][t]; mx = fmaxf(mx, sc[t]); }
            float ssum = 0.0f;
            #pragma unroll
            for (int t = 0; t < SEQ; ++t) { float e = __expf(sc[t] - mx); sc[t] = e; ssum += e; }
            float inv = frcp_(ssum);
            #pragma unroll
            for (int t = 0; t < SEQ; ++t) {
                float a = sc[t] * inv;
                S.attnw[m][t] = a;
                S.asum[m][t] += a;
            }
        }
        __syncthreads();
        // context -> ctxT[j][e]
        if (tid < 256) {
            int e = tid >> 7, j = tid & 127;
            float a = 0.0f;
            #pragma unroll
            for (int t = 0; t < SEQ; ++t)
                a = fmaf(S.attnw[e][t], (float)S.ench[t][e][j], a);
            S.ctxT[j][e] = a;
        }
        __syncthreads();
        // preload for s=0
        {
            const _Float16* hr = &S.hbuf[cur][l][0];
            #pragma unroll
            for (int kt = 0; kt < 4; ++kt) af[kt] = *(const half8*)&hr[32 * kt + 8 * q];
            xv = *(const f32x4*)&S.ctxT[0][4 * q];
        }
        // decoder LSTM: 129 steps, one barrier each
        for (int s = 0; s <= HDIM; ++s) {
            f32x4 acc[4];
            #pragma unroll
            for (int g = 0; g < 4; ++g)
                #pragma unroll
                for (int r = 0; r < 4; ++r)
                    acc[g][r] = fmaf(xv[r], wihg[g], bg[g]);
            #pragma unroll
            for (int g = 0; g < 4; ++g)
                #pragma unroll
                for (int kt = 0; kt < 4; ++kt)
                    acc[g] = __builtin_amdgcn_mfma_f32_16x16x32_f16(af[kt], whh[g][kt], acc[g], 0, 0, 0);
            float s0 = __shfl_xor(acc[0][1], 16, 64);
            float s1 = __shfl_xor(acc[1][1], 16, 64);
            float s2 = __shfl_xor(acc[2][1], 16, 64);
            float s3 = __shfl_xor(acc[3][1], 16, 64);
            float v0 = (q == 0) ? acc[0][0] : s0;
            float v1 = (q == 0) ? acc[1][0] : s1;
            float v2 = (q == 0) ? acc[2][0] : s2;
            float v3 = (q == 0) ? acc[3][0] : s3;
            float ig = fsig_(v0), fg = fsig_(v1), gg = ftanh_(v2), og = fsig_(v3);
            c = fmaf(fg, c, ig * gg);
            float hn = og * ftanh_(c);
            int nxt = cur ^ 1;
            if (q < 2) S.hbuf[nxt][q][16 * w + l] = (_Float16)hn;
            __syncthreads();
            cur = nxt;
            if (s < HDIM) {
                const _Float16* hr = &S.hbuf[cur][l][0];
                #pragma unroll
                for (int kt = 0; kt < 4; ++kt) af[kt] = *(const half8*)&hr[32 * kt + 8 * q];
                xv = *(const f32x4*)&S.ctxT[s + 1][4 * q];
            }
        }
        // output projection -> next x
        if (tid < 32) {
            int m = tid >> 4, part = tid & 15;
            half8 hv = *(const half8*)&S.hbuf[cur][m][part * 8];
            float s = 0.0f;
            #pragma unroll
            for (int i = 0; i < 8; ++i) s = fmaf((float)hv[i], S.wf[part * 8 + i], s);
            s += __shfl_down(s, 8, 16);
            s += __shfl_down(s, 4, 16);
            s += __shfl_down(s, 2, 16);
            s += __shfl_down(s, 1, 16);
            if (part == 0) {
                float o = s + bf0;
                out[(b0 + m) * TLEN + d] = o;
                S.ctxT[HDIM][m] = o;
            }
        }
        __syncthreads();
    }

    // total_attn [B, 14, 1]
    if (tid < EPB * SEQ) {
        int m = tid / SEQ, t = tid % SEQ;
        out[B * TLEN + (b0 + m) * SEQ + t] = S.asum[m][t];
    }
}

extern "C" void kernel_launch(void* const* d_in, const int* in_sizes, int n_in,
                              void* d_out, int out_size, void* d_ws, size_t ws_size,
                              hipStream_t stream) {
    const float* inputs = (const float*)d_in[0];
    const float* Wih_e = (const float*)d_in[2];
    const float* Whh_e = (const float*)d_in[3];
    const float* b_e   = (const float*)d_in[4];
    const float* Wih_d = (const float*)d_in[5];
    const float* Whh_d = (const float*)d_in[6];
    const float* b_d   = (const float*)d_in[7];
    const float* We    = (const float*)d_in[8];
    const float* Wd    = (const float*)d_in[9];
    const float* Wv    = (const float*)d_in[10];
    const float* Wf    = (const float*)d_in[11];
    const float* bfp   = (const float*)d_in[12];
    float* out = (float*)d_out;

    const int B = in_sizes[0] / SEQ;  // 512

    seq2seq_kernel<<<dim3(B / EPB), dim3(NTHR), 0, stream>>>(
        inputs, Wih_e, Whh_e, b_e, Wih_d, Whh_d, b_d, We, Wd, Wv, Wf, bfp, out, B);
}